// Round 18
// baseline (1537.471 us; speedup 1.0000x reference)
//
#include <hip/hip_runtime.h>

#define BATCH 2
#define NH    16
#define SEQ   2048
#define DH    64
#define NW    8             // waves per block
#define QR    8             // q-rows per block
#define KSPAN 256           // k-cols per wave
#define CHUNK 64            // k-cols per chunk
#define NCHK  (KSPAN/CHUNK) // 4 chunks per wave
#define SUBT  32            // MFMA subtile cols

typedef __attribute__((ext_vector_type(8))) short          bf16x8;
typedef __attribute__((ext_vector_type(4))) float          f32x4;
typedef __attribute__((ext_vector_type(2))) unsigned int   u32x2;
typedef __attribute__((ext_vector_type(4))) int            i32x4;

__device__ __forceinline__ unsigned short f2bf(float f) {   // RNE (Q only)
    union { float f; unsigned int i; } c;
    c.f = f;
    unsigned int x = c.i;
    x += 0x7fffu + ((x >> 16) & 1u);
    return (unsigned short)(x >> 16);
}
__device__ __forceinline__ unsigned int pkt(float lo, float hi) {   // trunc bf16 pair
    union { float f; unsigned int u; } a, b;
    a.f = lo; b.f = hi;
    return (b.u & 0xFFFF0000u) | (a.u >> 16);
}
__device__ __forceinline__ float bfu2f(unsigned short u) {
    union { unsigned int i; float f; } c;
    c.i = ((unsigned int)u) << 16;
    return c.f;
}

// Single-pass SDPA, q-tile = 8 rows: P held in LDS (bf16) until row-sums done.
template<bool ISBYTE>
__global__ __launch_bounds__(512, 4)
void sdpa_fused(const float* __restrict__ qp,
                const float* __restrict__ kp,
                const float* __restrict__ vp,
                const void*  __restrict__ mp,
                const float* __restrict__ bp,
                float* __restrict__ outp,
                float* __restrict__ attnp)
{
    // Pbig[row 0..7][k 0..2047] bf16, row stride 4096B, XOR-swizzled (^((row&7)<<4))
    __shared__ __align__(16) unsigned short Pbig[QR * 2048];          // 32 KB
    // Arena[w]: phase1 = raw-score pivot (8x64 f32, XOR-swz); end = accO deposit (8x64 f32)
    __shared__ __align__(16) float Arena[NW][QR * 64];                // 16 KB
    __shared__ float Lsum[NW][QR];                                    // row-sum partials

    const int tid  = threadIdx.x;
    const int w    = tid >> 6;          // wave id: owns k in [256w, 256w+256)
    const int lane = tid & 63;
    const int l15  = lane & 15;
    const int g    = lane >> 4;

    // mask layout probe — block-uniform exit BEFORE any barrier
    const unsigned int* mw = (const unsigned int*)mp;
    if ((__any((int)(mw[lane & 31] > 1u)) != 0) != ISBYTE) return;

    const int bid  = blockIdx.x;
    const int orig = (bid & 7) * 1024 + (bid >> 3);  // bijective XCD swizzle (8192 blocks)
    const int h    = orig >> 9;                      // 2 heads per XCD
    const int rem  = orig & 511;
    const int qt   = rem >> 1;                       // 0..255
    const int b    = rem & 1;                        // b-pair adjacent -> bias L2 share
    const int bh   = b * NH + h;
    const int qbase = qt * QR;
    const int kw   = w * KSPAN;

    const float* kbh = kp + (size_t)bh * SEQ * DH;
    const float* vbh = vp + (size_t)bh * SEQ * DH;
    char* pivot = (char*)&Arena[w][0];               // 8 rows x 256B
    char* pbig  = (char*)Pbig;

    // Q fragment (B-operand of swapped QK^T), prescaled by 1/8.
    // Rows 8..15 duplicate rows 0..7 (clamped) -> D cols 8..15 are ignored dups.
    bf16x8 qf0, qf1;
    {
        const float* qb = qp + ((size_t)bh * SEQ + qbase + (l15 & 7)) * DH + g * 8;
        #pragma unroll
        for (int j = 0; j < 8; ++j) {
            qf0[j] = (short)f2bf(qb[j]      * 0.125f);
            qf1[j] = (short)f2bf(qb[32 + j] * 0.125f);
        }
    }

    struct KS { f32x4 k[2][4]; };
    auto load_k = [&](int tk, KS& R) {               // tk = subtile idx 0..7 in wave span
        const int kb = kw + tk * SUBT;
        #pragma unroll
        for (int mb = 0; mb < 2; ++mb) {
            const float* arow = kbh + (size_t)(kb + 16 * mb + l15) * DH + g * 8;
            R.k[mb][0] = *(const f32x4*)(arow);
            R.k[mb][1] = *(const f32x4*)(arow + 4);
            R.k[mb][2] = *(const f32x4*)(arow + 32);
            R.k[mb][3] = *(const f32x4*)(arow + 36);
        }
    };

    auto produce = [&](const KS& R, int s2) {        // s2 = subtile within chunk (0/1)
        #pragma unroll
        for (int mb = 0; mb < 2; ++mb) {
            union { bf16x8 v; unsigned int u[4]; } A0, A1;
            A0.u[0] = pkt(R.k[mb][0][0], R.k[mb][0][1]);
            A0.u[1] = pkt(R.k[mb][0][2], R.k[mb][0][3]);
            A0.u[2] = pkt(R.k[mb][1][0], R.k[mb][1][1]);
            A0.u[3] = pkt(R.k[mb][1][2], R.k[mb][1][3]);
            A1.u[0] = pkt(R.k[mb][2][0], R.k[mb][2][1]);
            A1.u[1] = pkt(R.k[mb][2][2], R.k[mb][2][3]);
            A1.u[2] = pkt(R.k[mb][3][0], R.k[mb][3][1]);
            A1.u[3] = pkt(R.k[mb][3][2], R.k[mb][3][3]);
            f32x4 c = (f32x4){0.f, 0.f, 0.f, 0.f};
            __builtin_amdgcn_s_setprio(1);
            c = __builtin_amdgcn_mfma_f32_16x16x32_bf16(A0.v, qf0, c, 0, 0, 0);
            c = __builtin_amdgcn_mfma_f32_16x16x32_bf16(A1.v, qf1, c, 0, 0, 0);
            __builtin_amdgcn_s_setprio(0);
            // raw scores -> pivot [q=l15<8][col = 32*s2+16*mb+4*g .. +3], XOR-swizzled
            if (l15 < 8) {
                const int byo = (128 * s2 + 64 * mb + 16 * g) ^ (l15 << 4);
                *(f32x4*)(pivot + l15 * 256 + byo) = c;
            }
        }
    };

    auto load_bias = [&](int c, f32x4* B) {          // contiguous: 4 rows x 256B per instr
        #pragma unroll
        for (int i = 0; i < 2; ++i)
            B[i] = *(const f32x4*)(bp + ((size_t)h * SEQ + qbase + 4 * i + g) * SEQ
                                   + kw + c * CHUNK + 4 * l15);
    };

    float rs[2] = {0.f, 0.f};                        // row partials (row = 4i+g)

    auto consume = [&](int c, const f32x4* B) {
        #pragma unroll
        for (int i = 0; i < 2; ++i) {
            const int qr = 4 * i + g;                // local row 0..7
            int m4[4];
            if constexpr (ISBYTE) {
                unsigned int mk = *(const unsigned int*)((const unsigned char*)mp +
                    ((size_t)b * SEQ + qbase + qr) * SEQ + kw + c * CHUNK + 4 * l15);
                #pragma unroll
                for (int j = 0; j < 4; ++j) m4[j] = (int)((mk >> (8 * j)) & 0xFFu);
            } else {
                i32x4 mk = *(const i32x4*)((const int*)mp +
                    ((size_t)b * SEQ + qbase + qr) * SEQ + kw + c * CHUNK + 4 * l15);
                #pragma unroll
                for (int j = 0; j < 4; ++j) m4[j] = mk[j];
            }
            f32x4 p = *(const f32x4*)(pivot + qr * 256 + ((16 * l15) ^ (qr << 4)));
            f32x4 pa;
            #pragma unroll
            for (int j = 0; j < 4; ++j)
                pa[j] = m4[j] ? 0.0f : __expf(p[j] + B[i][j]);
            rs[i] += pa[0] + pa[1] + pa[2] + pa[3];
            u32x2 pw;
            pw[0] = pkt(pa[0], pa[1]);
            pw[1] = pkt(pa[2], pa[3]);
            const int byo = (2 * kw + 128 * c + 8 * l15) ^ (qr << 4);
            *(u32x2*)(pbig + qr * 4096 + byo) = pw;
        }
    };

    f32x4 accO[4];   // accO[nb][rr] = O[q=qbase+4g+rr][d=16nb+l15] (rows 0..7 valid)
    #pragma unroll
    for (int i = 0; i < 4; ++i) accO[i] = (f32x4){0.f, 0.f, 0.f, 0.f};

    auto pv = [&](int c) {
        #pragma unroll
        for (int ks2 = 0; ks2 < 2; ++ks2) {
            const int colg = kw + (2 * c + ks2) * SUBT;
            // A-frag: P[q = l15&7 (dup)][k=colg+8g .. +7] from Pbig
            const int byo = (2 * colg + 16 * g) ^ ((l15 & 7) << 4);
            bf16x8 pf = *(const bf16x8*)(pbig + (l15 & 7) * 4096 + byo);
            const float* vb2 = vbh + (size_t)colg * DH + 512 * g + l15;
            union { bf16x8 v; unsigned int u[4]; } vf[4];
            #pragma unroll
            for (int nb = 0; nb < 4; ++nb)
                #pragma unroll
                for (int i2 = 0; i2 < 4; ++i2)
                    vf[nb].u[i2] = pkt(vb2[(2 * i2) * 64 + 16 * nb],
                                       vb2[(2 * i2 + 1) * 64 + 16 * nb]);
            __builtin_amdgcn_s_setprio(1);
            #pragma unroll
            for (int nb = 0; nb < 4; ++nb)
                accO[nb] = __builtin_amdgcn_mfma_f32_16x16x32_bf16(pf, vf[nb].v, accO[nb], 0, 0, 0);
            __builtin_amdgcn_s_setprio(0);
        }
    };

    // ================= phase 1: 4 chunks, bias D=1-ahead, K D=2 ring =================
    {
        KS RA, RB;
        f32x4 BA[2], BB[2];
        load_k(0, RA);
        load_k(1, RB);
        load_bias(0, BA);

        #pragma unroll
        for (int c = 0; c < NCHK; ++c) {
            f32x4* Bcur = (c & 1) ? BB : BA;
            f32x4* Bnxt = (c & 1) ? BA : BB;
            if (c < NCHK - 1) load_bias(c + 1, Bnxt);
            produce(RA, 0);  load_k((2 * c + 2) & 7, RA);
            produce(RB, 1);  load_k((2 * c + 3) & 7, RB);
            consume(c, Bcur);
            pv(c);
        }
    }

    // row-sum partials -> Lsum; accO rows 0..7 -> Arena (unions the now-dead pivot)
    #pragma unroll
    for (int i = 0; i < 2; ++i) {
        float t = rs[i];
        t += __shfl_xor(t, 1, 64);
        t += __shfl_xor(t, 2, 64);
        t += __shfl_xor(t, 4, 64);
        t += __shfl_xor(t, 8, 64);
        if (l15 == 0) Lsum[w][4 * i + g] = t;
    }
    if (g < 2) {
        #pragma unroll
        for (int rr = 0; rr < 4; ++rr)
            #pragma unroll
            for (int nb = 0; nb < 4; ++nb)
                Arena[w][(4 * g + rr) * 64 + 16 * nb + l15] = accO[nb][rr];
    }

    __syncthreads();

    // ================= phase 2: normalize own span, write attn ONCE =================
    float rv[2];
    #pragma unroll
    for (int i = 0; i < 2; ++i) {
        float s = 0.f;
        #pragma unroll
        for (int ww = 0; ww < NW; ++ww) s += Lsum[ww][4 * i + g];
        rv[i] = 1.0f / s;
    }

    #pragma unroll
    for (int i = 0; i < 2; ++i) {
        const int qr = 4 * i + g;
        #pragma unroll
        for (int u = 0; u < 2; ++u) {
            const int byo = (2 * kw + 256 * u + 16 * l15) ^ (qr << 4);
            bf16x8 pb8 = *(const bf16x8*)(pbig + qr * 4096 + byo);
            f32x4 o0, o1;
            #pragma unroll
            for (int j = 0; j < 4; ++j) {
                o0[j] = bfu2f((unsigned short)pb8[j])     * rv[i];
                o1[j] = bfu2f((unsigned short)pb8[4 + j]) * rv[i];
            }
            float* ap = attnp + ((size_t)bh * SEQ + qbase + qr) * SEQ
                        + kw + u * 128 + 8 * l15;
            *(f32x4*)ap       = o0;
            *(f32x4*)(ap + 4) = o1;
        }
    }

    // out: wave 0 combines the 8 deposits + normalizes (8 rows x 64 d)
    if (w == 0) {
        const int d = lane;
        #pragma unroll
        for (int r = 0; r < QR; ++r) {
            float s = 0.f, o = 0.f;
            #pragma unroll
            for (int ww = 0; ww < NW; ++ww) {
                s += Lsum[ww][r];
                o += Arena[ww][r * 64 + d];
            }
            outp[((size_t)bh * SEQ + qbase + r) * DH + d] = o / s;
        }
    }
}

extern "C" void kernel_launch(void* const* d_in, const int* in_sizes, int n_in,
                              void* d_out, int out_size, void* d_ws, size_t ws_size,
                              hipStream_t stream) {
    const float* qp = (const float*)d_in[0];
    const float* kp = (const float*)d_in[1];
    const float* vp = (const float*)d_in[2];
    const void*  mp = d_in[3];
    const float* bp = (const float*)d_in[4];

    float* outp  = (float*)d_out;
    float* attnp = outp + (size_t)BATCH * NH * SEQ * DH;   // out first, then attn (f32)

    dim3 grid(BATCH * NH * (SEQ / QR)), block(512);        // 8192 blocks x 8 waves
    // mask layout resolved on-device; mismatched instantiation exits immediately
    sdpa_fused<true ><<<grid, block, 0, stream>>>(qp, kp, vp, mp, bp, outp, attnp);
    sdpa_fused<false><<<grid, block, 0, stream>>>(qp, kp, vp, mp, bp, outp, attnp);
}

// Round 19
// 995.420 us; speedup vs baseline: 1.5445x; 1.5445x over previous
//
#include <hip/hip_runtime.h>

#define BATCH 2
#define NH    16
#define SEQ   2048
#define DH    64
#define NW    8             // waves per block
#define QR    8             // q-rows per block
#define KSPAN 256           // k-cols per wave
#define CHUNK 64            // k-cols per chunk
#define NCHK  (KSPAN/CHUNK) // 4 chunks per wave
#define SUBT  32            // MFMA subtile cols

typedef __attribute__((ext_vector_type(8))) short          bf16x8;
typedef __attribute__((ext_vector_type(4))) float          f32x4;
typedef __attribute__((ext_vector_type(2))) unsigned int   u32x2;
typedef __attribute__((ext_vector_type(4))) int            i32x4;

__device__ __forceinline__ unsigned short f2bf(float f) {   // RNE (Q only)
    union { float f; unsigned int i; } c;
    c.f = f;
    unsigned int x = c.i;
    x += 0x7fffu + ((x >> 16) & 1u);
    return (unsigned short)(x >> 16);
}
__device__ __forceinline__ unsigned int pkt(float lo, float hi) {   // trunc bf16 pair
    union { float f; unsigned int u; } a, b;
    a.f = lo; b.f = hi;
    return (b.u & 0xFFFF0000u) | (a.u >> 16);
}
__device__ __forceinline__ float bfu2f(unsigned short u) {
    union { unsigned int i; float f; } c;
    c.i = ((unsigned int)u) << 16;
    return c.f;
}

// Single-pass SDPA, q-tile = 8 rows: P held in LDS (bf16) until row-sums done.
// LB(512,2): relaxed budget — r18's (512,4) forced 64-VGPR spills (+2.7 GB scratch).
template<bool ISBYTE>
__global__ __launch_bounds__(512, 2)
void sdpa_fused(const float* __restrict__ qp,
                const float* __restrict__ kp,
                const float* __restrict__ vp,
                const void*  __restrict__ mp,
                const float* __restrict__ bp,
                float* __restrict__ outp,
                float* __restrict__ attnp)
{
    // Pbig[row 0..7][k 0..2047] bf16, row stride 4096B, XOR-swizzled (^(row<<4))
    __shared__ __align__(16) unsigned short Pbig[QR * 2048];          // 32 KB
    // Arena[w]: phase1 = raw-score pivot (8x64 f32, XOR-swz); end = accO deposit
    __shared__ __align__(16) float Arena[NW][QR * 64];                // 16 KB
    __shared__ float Lsum[NW][QR];                                    // row-sum partials

    const int tid  = threadIdx.x;
    const int w    = tid >> 6;          // wave id: owns k in [256w, 256w+256)
    const int lane = tid & 63;
    const int l15  = lane & 15;
    const int g    = lane >> 4;

    // mask layout probe — block-uniform exit BEFORE any barrier
    const unsigned int* mw = (const unsigned int*)mp;
    if ((__any((int)(mw[lane & 31] > 1u)) != 0) != ISBYTE) return;

    const int bid  = blockIdx.x;
    const int orig = (bid & 7) * 1024 + (bid >> 3);  // bijective XCD swizzle (8192 blocks)
    const int h    = orig >> 9;                      // 2 heads per XCD
    const int rem  = orig & 511;
    const int qt   = rem >> 1;                       // 0..255
    const int b    = rem & 1;                        // b-pair adjacent -> bias L2 share
    const int bh   = b * NH + h;
    const int qbase = qt * QR;
    const int kw   = w * KSPAN;

    const float* kbh = kp + (size_t)bh * SEQ * DH;
    const float* vbh = vp + (size_t)bh * SEQ * DH;
    char* pivot = (char*)&Arena[w][0];               // 8 rows x 256B
    char* pbig  = (char*)Pbig;

    // Q fragment (B-operand of swapped QK^T), prescaled by 1/8.
    // Rows 8..15 duplicate rows 0..7 (clamped) -> D cols 8..15 are ignored dups.
    bf16x8 qf0, qf1;
    {
        const float* qb = qp + ((size_t)bh * SEQ + qbase + (l15 & 7)) * DH + g * 8;
        #pragma unroll
        for (int j = 0; j < 8; ++j) {
            qf0[j] = (short)f2bf(qb[j]      * 0.125f);
            qf1[j] = (short)f2bf(qb[32 + j] * 0.125f);
        }
    }

    struct KS { f32x4 k[2][4]; };
    auto load_k = [&](int tk, KS& R) {               // tk = subtile idx 0..7 in wave span
        const int kb = kw + tk * SUBT;
        #pragma unroll
        for (int mb = 0; mb < 2; ++mb) {
            const float* arow = kbh + (size_t)(kb + 16 * mb + l15) * DH + g * 8;
            R.k[mb][0] = *(const f32x4*)(arow);
            R.k[mb][1] = *(const f32x4*)(arow + 4);
            R.k[mb][2] = *(const f32x4*)(arow + 32);
            R.k[mb][3] = *(const f32x4*)(arow + 36);
        }
    };

    auto produce = [&](const KS& R, int s2) {        // s2 = subtile within chunk (0/1)
        #pragma unroll
        for (int mb = 0; mb < 2; ++mb) {
            union { bf16x8 v; unsigned int u[4]; } A0, A1;
            A0.u[0] = pkt(R.k[mb][0][0], R.k[mb][0][1]);
            A0.u[1] = pkt(R.k[mb][0][2], R.k[mb][0][3]);
            A0.u[2] = pkt(R.k[mb][1][0], R.k[mb][1][1]);
            A0.u[3] = pkt(R.k[mb][1][2], R.k[mb][1][3]);
            A1.u[0] = pkt(R.k[mb][2][0], R.k[mb][2][1]);
            A1.u[1] = pkt(R.k[mb][2][2], R.k[mb][2][3]);
            A1.u[2] = pkt(R.k[mb][3][0], R.k[mb][3][1]);
            A1.u[3] = pkt(R.k[mb][3][2], R.k[mb][3][3]);
            f32x4 c = (f32x4){0.f, 0.f, 0.f, 0.f};
            __builtin_amdgcn_s_setprio(1);
            c = __builtin_amdgcn_mfma_f32_16x16x32_bf16(A0.v, qf0, c, 0, 0, 0);
            c = __builtin_amdgcn_mfma_f32_16x16x32_bf16(A1.v, qf1, c, 0, 0, 0);
            __builtin_amdgcn_s_setprio(0);
            // raw scores -> pivot [q=l15<8][col = 32*s2+16*mb+4*g .. +3], XOR-swizzled
            if (l15 < 8) {
                const int byo = (128 * s2 + 64 * mb + 16 * g) ^ (l15 << 4);
                *(f32x4*)(pivot + l15 * 256 + byo) = c;
            }
        }
    };

    auto load_bias = [&](int c, f32x4* B) {          // contiguous: 4 rows x 256B per instr
        #pragma unroll
        for (int i = 0; i < 2; ++i)
            B[i] = *(const f32x4*)(bp + ((size_t)h * SEQ + qbase + 4 * i + g) * SEQ
                                   + kw + c * CHUNK + 4 * l15);
    };

    float rs[2] = {0.f, 0.f};                        // row partials (row = 4i+g)

    auto consume = [&](int c, const f32x4* B) {
        #pragma unroll
        for (int i = 0; i < 2; ++i) {
            const int qr = 4 * i + g;                // local row 0..7
            int m4[4];
            if constexpr (ISBYTE) {
                unsigned int mk = *(const unsigned int*)((const unsigned char*)mp +
                    ((size_t)b * SEQ + qbase + qr) * SEQ + kw + c * CHUNK + 4 * l15);
                #pragma unroll
                for (int j = 0; j < 4; ++j) m4[j] = (int)((mk >> (8 * j)) & 0xFFu);
            } else {
                i32x4 mk = *(const i32x4*)((const int*)mp +
                    ((size_t)b * SEQ + qbase + qr) * SEQ + kw + c * CHUNK + 4 * l15);
                #pragma unroll
                for (int j = 0; j < 4; ++j) m4[j] = mk[j];
            }
            f32x4 p = *(const f32x4*)(pivot + qr * 256 + ((16 * l15) ^ (qr << 4)));
            f32x4 pa;
            #pragma unroll
            for (int j = 0; j < 4; ++j)
                pa[j] = m4[j] ? 0.0f : __expf(p[j] + B[i][j]);
            rs[i] += pa[0] + pa[1] + pa[2] + pa[3];
            u32x2 pw;
            pw[0] = pkt(pa[0], pa[1]);
            pw[1] = pkt(pa[2], pa[3]);
            const int byo = (2 * kw + 128 * c + 8 * l15) ^ (qr << 4);
            *(u32x2*)(pbig + qr * 4096 + byo) = pw;
        }
    };

    f32x4 accO[4];   // accO[nb][rr] = O[q=qbase+4g+rr][d=16nb+l15] (rows 0..7 valid)
    #pragma unroll
    for (int i = 0; i < 4; ++i) accO[i] = (f32x4){0.f, 0.f, 0.f, 0.f};

    auto pv = [&](int c) {
        #pragma unroll
        for (int ks2 = 0; ks2 < 2; ++ks2) {
            const int colg = kw + (2 * c + ks2) * SUBT;
            // A-frag: P[q = l15&7 (dup)][k=colg+8g .. +7] from Pbig
            const int byo = (2 * colg + 16 * g) ^ ((l15 & 7) << 4);
            bf16x8 pf = *(const bf16x8*)(pbig + (l15 & 7) * 4096 + byo);
            const float* vb2 = vbh + (size_t)colg * DH + 512 * g + l15;
            union { bf16x8 v; unsigned int u[4]; } vf[4];
            #pragma unroll
            for (int nb = 0; nb < 4; ++nb)
                #pragma unroll
                for (int i2 = 0; i2 < 4; ++i2)
                    vf[nb].u[i2] = pkt(vb2[(2 * i2) * 64 + 16 * nb],
                                       vb2[(2 * i2 + 1) * 64 + 16 * nb]);
            __builtin_amdgcn_s_setprio(1);
            #pragma unroll
            for (int nb = 0; nb < 4; ++nb)
                accO[nb] = __builtin_amdgcn_mfma_f32_16x16x32_bf16(pf, vf[nb].v, accO[nb], 0, 0, 0);
            __builtin_amdgcn_s_setprio(0);
        }
    };

    // ================= phase 1: 4 chunks, bias D=1-ahead, K D=2 ring =================
    {
        KS RA, RB;
        f32x4 BA[2], BB[2];
        load_k(0, RA);
        load_k(1, RB);
        load_bias(0, BA);

        #pragma unroll
        for (int c = 0; c < NCHK; ++c) {
            f32x4* Bcur = (c & 1) ? BB : BA;
            f32x4* Bnxt = (c & 1) ? BA : BB;
            if (c < NCHK - 1) load_bias(c + 1, Bnxt);
            produce(RA, 0);  load_k((2 * c + 2) & 7, RA);
            produce(RB, 1);  load_k((2 * c + 3) & 7, RB);
            consume(c, Bcur);
            pv(c);
        }
    }

    // row-sum partials -> Lsum; accO rows 0..7 -> Arena (unions the now-dead pivot)
    #pragma unroll
    for (int i = 0; i < 2; ++i) {
        float t = rs[i];
        t += __shfl_xor(t, 1, 64);
        t += __shfl_xor(t, 2, 64);
        t += __shfl_xor(t, 4, 64);
        t += __shfl_xor(t, 8, 64);
        if (l15 == 0) Lsum[w][4 * i + g] = t;
    }
    if (g < 2) {
        #pragma unroll
        for (int rr = 0; rr < 4; ++rr)
            #pragma unroll
            for (int nb = 0; nb < 4; ++nb)
                Arena[w][(4 * g + rr) * 64 + 16 * nb + l15] = accO[nb][rr];
    }

    __syncthreads();

    // ================= phase 2: normalize own span, write attn ONCE =================
    float rv[2];
    #pragma unroll
    for (int i = 0; i < 2; ++i) {
        float s = 0.f;
        #pragma unroll
        for (int ww = 0; ww < NW; ++ww) s += Lsum[ww][4 * i + g];
        rv[i] = 1.0f / s;
    }

    #pragma unroll
    for (int i = 0; i < 2; ++i) {
        const int qr = 4 * i + g;
        #pragma unroll
        for (int u = 0; u < 2; ++u) {
            const int byo = (2 * kw + 256 * u + 16 * l15) ^ (qr << 4);
            bf16x8 pb8 = *(const bf16x8*)(pbig + qr * 4096 + byo);
            f32x4 o0, o1;
            #pragma unroll
            for (int j = 0; j < 4; ++j) {
                o0[j] = bfu2f((unsigned short)pb8[j])     * rv[i];
                o1[j] = bfu2f((unsigned short)pb8[4 + j]) * rv[i];
            }
            float* ap = attnp + ((size_t)bh * SEQ + qbase + qr) * SEQ
                        + kw + u * 128 + 8 * l15;
            *(f32x4*)ap       = o0;
            *(f32x4*)(ap + 4) = o1;
        }
    }

    // out: wave 0 combines the 8 deposits + normalizes (8 rows x 64 d)
    if (w == 0) {
        const int d = lane;
        #pragma unroll
        for (int r = 0; r < QR; ++r) {
            float s = 0.f, o = 0.f;
            #pragma unroll
            for (int ww = 0; ww < NW; ++ww) {
                s += Lsum[ww][r];
                o += Arena[ww][r * 64 + d];
            }
            outp[((size_t)bh * SEQ + qbase + r) * DH + d] = o / s;
        }
    }
}

extern "C" void kernel_launch(void* const* d_in, const int* in_sizes, int n_in,
                              void* d_out, int out_size, void* d_ws, size_t ws_size,
                              hipStream_t stream) {
    const float* qp = (const float*)d_in[0];
    const float* kp = (const float*)d_in[1];
    const float* vp = (const float*)d_in[2];
    const void*  mp = d_in[3];
    const float* bp = (const float*)d_in[4];

    float* outp  = (float*)d_out;
    float* attnp = outp + (size_t)BATCH * NH * SEQ * DH;   // out first, then attn (f32)

    dim3 grid(BATCH * NH * (SEQ / QR)), block(512);        // 8192 blocks x 8 waves
    // mask layout resolved on-device; mismatched instantiation exits immediately
    sdpa_fused<true ><<<grid, block, 0, stream>>>(qp, kp, vp, mp, bp, outp, attnp);
    sdpa_fused<false><<<grid, block, 0, stream>>>(qp, kp, vp, mp, bp, outp, attnp);
}

// Round 20
// 705.240 us; speedup vs baseline: 2.1801x; 1.4115x over previous
//
#include <hip/hip_runtime.h>

#define BATCH 2
#define NH    16
#define SEQ   2048
#define DH    64
#define NW    8             // waves per block
#define KSPAN 256           // k-cols per wave
#define CHUNK 64            // k-cols per chunk
#define NCHK  (KSPAN/CHUNK) // 4 chunks per wave
#define SUBT  32            // MFMA subtile cols
#define VSTR  40            // VT row stride (shorts): 32 k + 8 pad

typedef __attribute__((ext_vector_type(8))) short          bf16x8;
typedef __attribute__((ext_vector_type(4))) float          f32x4;
typedef __attribute__((ext_vector_type(2))) unsigned int   u32x2;
typedef __attribute__((ext_vector_type(4))) int            i32x4;

__device__ __forceinline__ unsigned short f2bf(float f) {   // RNE (Q only)
    union { float f; unsigned int i; } c;
    c.f = f;
    unsigned int x = c.i;
    x += 0x7fffu + ((x >> 16) & 1u);
    return (unsigned short)(x >> 16);
}
__device__ __forceinline__ unsigned int pkt(float lo, float hi) {   // trunc bf16 pair
    union { float f; unsigned int u; } a, b;
    a.f = lo; b.f = hi;
    return (b.u & 0xFFFF0000u) | (a.u >> 16);
}
__device__ __forceinline__ unsigned short f2bft(float f) {  // trunc single
    union { float f; unsigned int u; } c;
    c.f = f;
    return (unsigned short)(c.u >> 16);
}
__device__ __forceinline__ float bfu2f(unsigned short u) {
    union { unsigned int i; float f; } c;
    c.i = ((unsigned int)u) << 16;
    return c.f;
}

// Single-pass SDPA (r17 geometry, QR=16) + coalesced V staging through LDS.
template<bool ISBYTE>
__global__ __launch_bounds__(512, 2)
void sdpa_fused(const float* __restrict__ qp,
                const float* __restrict__ kp,
                const float* __restrict__ vp,
                const void*  __restrict__ mp,
                const float* __restrict__ bp,
                float* __restrict__ outp,
                float* __restrict__ attnp)
{
    __shared__ __align__(16) unsigned short Pbig[16 * 2048];          // 64 KB
    __shared__ __align__(16) float Arena[NW][16 * CHUNK];             // 32 KB (pivot / accO)
    __shared__ __align__(16) unsigned short VTs[NW][DH * VSTR];       // 40 KB (V^T tiles)
    __shared__ float Lsum[NW][16];                                    // row-sum partials

    const int tid  = threadIdx.x;
    const int w    = tid >> 6;          // wave id: owns k in [256w, 256w+256)
    const int lane = tid & 63;
    const int l15  = lane & 15;
    const int g    = lane >> 4;

    // mask layout probe — block-uniform exit BEFORE any barrier
    const unsigned int* mw = (const unsigned int*)mp;
    if ((__any((int)(mw[lane & 31] > 1u)) != 0) != ISBYTE) return;

    const int bid  = blockIdx.x;
    const int orig = (bid & 7) * 512 + (bid >> 3);   // bijective XCD swizzle (4096 blocks)
    const int h    = orig >> 8;                      // 2 heads per XCD
    const int rem  = orig & 255;
    const int qt   = rem >> 1;
    const int b    = rem & 1;                        // b-pair adjacent -> bias L2 share
    const int bh   = b * NH + h;
    const int qbase = qt * 16;
    const int kw   = w * KSPAN;

    const float* kbh = kp + (size_t)bh * SEQ * DH;
    const float* vbh = vp + (size_t)bh * SEQ * DH;
    char* pivot = (char*)&Arena[w][0];               // 16 rows x 256B
    char* pbig  = (char*)Pbig;
    unsigned short* vt = &VTs[w][0];

    // Q fragment (B-operand of swapped QK^T), prescaled by 1/8
    bf16x8 qf0, qf1;
    {
        const float* qb = qp + ((size_t)bh * SEQ + qbase + l15) * DH + g * 8;
        #pragma unroll
        for (int j = 0; j < 8; ++j) {
            qf0[j] = (short)f2bf(qb[j]      * 0.125f);
            qf1[j] = (short)f2bf(qb[32 + j] * 0.125f);
        }
    }

    struct KS { f32x4 k[2][4]; };
    auto load_k = [&](int tk, KS& R) {               // tk = subtile idx 0..7 in wave span
        const int kb = kw + tk * SUBT;
        #pragma unroll
        for (int mb = 0; mb < 2; ++mb) {
            const float* arow = kbh + (size_t)(kb + 16 * mb + l15) * DH + g * 8;
            R.k[mb][0] = *(const f32x4*)(arow);
            R.k[mb][1] = *(const f32x4*)(arow + 4);
            R.k[mb][2] = *(const f32x4*)(arow + 32);
            R.k[mb][3] = *(const f32x4*)(arow + 36);
        }
    };

    auto produce = [&](const KS& R, int s2) {        // s2 = subtile within chunk (0/1)
        #pragma unroll
        for (int mb = 0; mb < 2; ++mb) {
            union { bf16x8 v; unsigned int u[4]; } A0, A1;
            A0.u[0] = pkt(R.k[mb][0][0], R.k[mb][0][1]);
            A0.u[1] = pkt(R.k[mb][0][2], R.k[mb][0][3]);
            A0.u[2] = pkt(R.k[mb][1][0], R.k[mb][1][1]);
            A0.u[3] = pkt(R.k[mb][1][2], R.k[mb][1][3]);
            A1.u[0] = pkt(R.k[mb][2][0], R.k[mb][2][1]);
            A1.u[1] = pkt(R.k[mb][2][2], R.k[mb][2][3]);
            A1.u[2] = pkt(R.k[mb][3][0], R.k[mb][3][1]);
            A1.u[3] = pkt(R.k[mb][3][2], R.k[mb][3][3]);
            f32x4 c = (f32x4){0.f, 0.f, 0.f, 0.f};
            __builtin_amdgcn_s_setprio(1);
            c = __builtin_amdgcn_mfma_f32_16x16x32_bf16(A0.v, qf0, c, 0, 0, 0);
            c = __builtin_amdgcn_mfma_f32_16x16x32_bf16(A1.v, qf1, c, 0, 0, 0);
            __builtin_amdgcn_s_setprio(0);
            const int byo = (128 * s2 + 64 * mb + 16 * g) ^ ((l15 & 7) << 4);
            *(f32x4*)(pivot + l15 * 256 + byo) = c;
        }
    };

    auto load_bias = [&](int c, f32x4* B) {          // contiguous: 4 rows x 256B per instr
        #pragma unroll
        for (int i = 0; i < 4; ++i)
            B[i] = *(const f32x4*)(bp + ((size_t)h * SEQ + qbase + 4 * i + g) * SEQ
                                   + kw + c * CHUNK + 4 * l15);
    };

    float rs[4] = {0.f, 0.f, 0.f, 0.f};              // row partials (row = 4i+g)

    auto consume = [&](int c, const f32x4* B) {
        #pragma unroll
        for (int i = 0; i < 4; ++i) {
            const int qr = 4 * i + g;                // local row 0..15
            int m4[4];
            if constexpr (ISBYTE) {
                unsigned int mk = *(const unsigned int*)((const unsigned char*)mp +
                    ((size_t)b * SEQ + qbase + qr) * SEQ + kw + c * CHUNK + 4 * l15);
                #pragma unroll
                for (int j = 0; j < 4; ++j) m4[j] = (int)((mk >> (8 * j)) & 0xFFu);
            } else {
                i32x4 mk = *(const i32x4*)((const int*)mp +
                    ((size_t)b * SEQ + qbase + qr) * SEQ + kw + c * CHUNK + 4 * l15);
                #pragma unroll
                for (int j = 0; j < 4; ++j) m4[j] = mk[j];
            }
            f32x4 p = *(const f32x4*)(pivot + qr * 256 + ((16 * l15) ^ ((qr & 7) << 4)));
            f32x4 pa;
            #pragma unroll
            for (int j = 0; j < 4; ++j)
                pa[j] = m4[j] ? 0.0f : __expf(p[j] + B[i][j]);
            rs[i] += pa[0] + pa[1] + pa[2] + pa[3];
            u32x2 pw;
            pw[0] = pkt(pa[0], pa[1]);
            pw[1] = pkt(pa[2], pa[3]);
            const int byo = (2 * kw + 128 * c + 8 * l15) ^ ((qr & 7) << 4);
            *(u32x2*)(pbig + qr * 4096 + byo) = pw;
        }
    };

    // ---- V pipeline: coalesced global loads (1KB/instr) -> regs -> VT LDS tile ----
    auto gload_v = [&](int colg, f32x4* Gv) {        // 32 rows x 64 d, fully coalesced
        const float* src = vbh + (size_t)colg * DH;
        #pragma unroll
        for (int q = 0; q < 8; ++q)
            Gv[q] = *(const f32x4*)(src + q * 256 + lane * 4);
    };
    auto stage_v = [&](const f32x4* Gv) {            // regs -> VT[d][k] bf16, stride 40
        #pragma unroll
        for (int q = 0; q < 8; ++q)
            #pragma unroll
            for (int jj = 0; jj < 4; ++jj)
                vt[(4 * (lane & 15) + jj) * VSTR + 4 * q + (lane >> 4)] = f2bft(Gv[q][jj]);
    };

    f32x4 accO[4];   // accO[nb][rr] = O[q=qbase+4g+rr][d=16nb+l15] (this wave's k-span)
    #pragma unroll
    for (int i = 0; i < 4; ++i) accO[i] = (f32x4){0.f, 0.f, 0.f, 0.f};

    auto pv_sub = [&](int colg) {                    // PV for one 32-k subtile from VT
        const int byo = (2 * colg + 16 * g) ^ ((l15 & 7) << 4);
        bf16x8 pf = *(const bf16x8*)(pbig + l15 * 4096 + byo);
        __builtin_amdgcn_s_setprio(1);
        #pragma unroll
        for (int nb = 0; nb < 4; ++nb) {
            bf16x8 vf = *(const bf16x8*)(&vt[(16 * nb + l15) * VSTR + 8 * g]);
            accO[nb] = __builtin_amdgcn_mfma_f32_16x16x32_bf16(pf, vf, accO[nb], 0, 0, 0);
        }
        __builtin_amdgcn_s_setprio(0);
    };

    // ================= phase 1: 4 chunks; bias D=1, K D=2, V D=1 pipelines ============
    {
        KS RA, RB;
        f32x4 BA[4], BB[4];
        f32x4 Gv[8];
        load_k(0, RA);
        load_k(1, RB);
        load_bias(0, BA);
        gload_v(kw, Gv);                             // V(c=0, sub0)

        #pragma unroll
        for (int c = 0; c < NCHK; ++c) {
            f32x4* Bcur = (c & 1) ? BB : BA;
            f32x4* Bnxt = (c & 1) ? BA : BB;
            if (c < NCHK - 1) load_bias(c + 1, Bnxt);
            produce(RA, 0);  load_k((2 * c + 2) & 7, RA);
            produce(RB, 1);  load_k((2 * c + 3) & 7, RB);
            consume(c, Bcur);
            // PV sub 0
            stage_v(Gv);                             // VT <- V(c,0)
            gload_v(kw + (2 * c + 1) * SUBT, Gv);    // issue V(c,1)
            pv_sub(kw + (2 * c) * SUBT);
            // PV sub 1
            stage_v(Gv);                             // VT <- V(c,1) (sub0 reads done: same-wave order)
            gload_v(kw + (((2 * c + 2) & 7) * SUBT), Gv);   // issue V(c+1,0); wraps harmlessly
            pv_sub(kw + (2 * c + 1) * SUBT);
        }
    }

    // row-sum partials -> Lsum; accO -> Arena (unions the now-dead pivot)
    #pragma unroll
    for (int i = 0; i < 4; ++i) {
        float t = rs[i];
        t += __shfl_xor(t, 1, 64);
        t += __shfl_xor(t, 2, 64);
        t += __shfl_xor(t, 4, 64);
        t += __shfl_xor(t, 8, 64);
        if (l15 == 0) Lsum[w][4 * i + g] = t;
    }
    #pragma unroll
    for (int rr = 0; rr < 4; ++rr)
        #pragma unroll
        for (int nb = 0; nb < 4; ++nb)
            Arena[w][(4 * g + rr) * 64 + 16 * nb + l15] = accO[nb][rr];

    __syncthreads();

    // ================= phase 2: normalize own span, write attn ONCE =================
    float rv[4];
    #pragma unroll
    for (int i = 0; i < 4; ++i) {
        float s = 0.f;
        #pragma unroll
        for (int ww = 0; ww < NW; ++ww) s += Lsum[ww][4 * i + g];
        rv[i] = 1.0f / s;
    }

    #pragma unroll
    for (int i = 0; i < 4; ++i) {
        const int qr = 4 * i + g;
        #pragma unroll
        for (int u = 0; u < 2; ++u) {
            const int byo = (2 * kw + 256 * u + 16 * l15) ^ ((qr & 7) << 4);
            bf16x8 pb8 = *(const bf16x8*)(pbig + qr * 4096 + byo);
            f32x4 o0, o1;
            #pragma unroll
            for (int j = 0; j < 4; ++j) {
                o0[j] = bfu2f((unsigned short)pb8[j])     * rv[i];
                o1[j] = bfu2f((unsigned short)pb8[4 + j]) * rv[i];
            }
            float* ap = attnp + ((size_t)bh * SEQ + qbase + qr) * SEQ
                        + kw + u * 128 + 8 * l15;
            *(f32x4*)ap       = o0;
            *(f32x4*)(ap + 4) = o1;
        }
    }

    // out: wave 0 combines the 8 deposits + normalizes (16 rows x 64 d)
    if (w == 0) {
        const int d = lane;
        #pragma unroll
        for (int r = 0; r < 16; ++r) {
            float s = 0.f, o = 0.f;
            #pragma unroll
            for (int ww = 0; ww < NW; ++ww) {
                s += Lsum[ww][r];
                o += Arena[ww][r * 64 + d];
            }
            outp[((size_t)bh * SEQ + qbase + r) * DH + d] = o / s;
        }
    }
}

extern "C" void kernel_launch(void* const* d_in, const int* in_sizes, int n_in,
                              void* d_out, int out_size, void* d_ws, size_t ws_size,
                              hipStream_t stream) {
    const float* qp = (const float*)d_in[0];
    const float* kp = (const float*)d_in[1];
    const float* vp = (const float*)d_in[2];
    const void*  mp = d_in[3];
    const float* bp = (const float*)d_in[4];

    float* outp  = (float*)d_out;
    float* attnp = outp + (size_t)BATCH * NH * SEQ * DH;   // out first, then attn (f32)

    dim3 grid(BATCH * NH * (SEQ / 16)), block(512);        // 4096 blocks x 8 waves
    // mask layout resolved on-device; mismatched instantiation exits immediately
    sdpa_fused<true ><<<grid, block, 0, stream>>>(qp, kp, vp, mp, bp, outp, attnp);
    sdpa_fused<false><<<grid, block, 0, stream>>>(qp, kp, vp, mp, bp, outp, attnp);
}

// Round 21
// 605.160 us; speedup vs baseline: 2.5406x; 1.1654x over previous
//
#include <hip/hip_runtime.h>

#define BATCH 2
#define NH    16
#define SEQ   2048
#define DH    64
#define NW    8             // waves per block
#define KSPAN 256           // k-cols per wave
#define CHUNK 64            // k-cols per chunk
#define NCHK  (KSPAN/CHUNK) // 4 chunks per wave
#define SUBT  32            // MFMA subtile cols

typedef __attribute__((ext_vector_type(8))) short          bf16x8;
typedef __attribute__((ext_vector_type(4))) float          f32x4;
typedef __attribute__((ext_vector_type(2))) unsigned int   u32x2;
typedef __attribute__((ext_vector_type(4))) int            i32x4;
typedef __attribute__((ext_vector_type(4))) _Float16       f16x4;

__device__ __forceinline__ unsigned short f2bf(float f) {   // RNE (Q only)
    union { float f; unsigned int i; } c;
    c.f = f;
    unsigned int x = c.i;
    x += 0x7fffu + ((x >> 16) & 1u);
    return (unsigned short)(x >> 16);
}
__device__ __forceinline__ unsigned int pkt(float lo, float hi) {   // trunc bf16 pair
    union { float f; unsigned int u; } a, b;
    a.f = lo; b.f = hi;
    return (b.u & 0xFFFF0000u) | (a.u >> 16);
}
__device__ __forceinline__ float bfu2f(unsigned short u) {
    union { unsigned int i; float f; } c;
    c.i = ((unsigned int)u) << 16;
    return c.f;
}

// Single-pass SDPA (r17 structure). LDS = 80 KB EXACTLY -> 2 blocks/CU:
//   Pbig 64 KB (unnormalized P bf16, full K) + ArenaH 16 KB (f16 raw-score pivot;
//   Lsum overlays it after phase 1; accO deposits go into Pbig at the end).
template<bool ISBYTE>
__global__ __launch_bounds__(512, 2)
void sdpa_fused(const float* __restrict__ qp,
                const float* __restrict__ kp,
                const float* __restrict__ vp,
                const void*  __restrict__ mp,
                const float* __restrict__ bp,
                float* __restrict__ outp,
                float* __restrict__ attnp)
{
    __shared__ __align__(16) unsigned short Pbig[16 * 2048];     // 64 KB
    __shared__ __align__(16) unsigned short ArenaH[NW][16 * 64]; // 16 KB (f16 pivot / Lsum)

    const int tid  = threadIdx.x;
    const int w    = tid >> 6;          // wave id: owns k in [256w, 256w+256)
    const int lane = tid & 63;
    const int l15  = lane & 15;
    const int g    = lane >> 4;

    // mask layout probe — block-uniform exit BEFORE any barrier
    const unsigned int* mw = (const unsigned int*)mp;
    if ((__any((int)(mw[lane & 31] > 1u)) != 0) != ISBYTE) return;

    const int bid  = blockIdx.x;
    const int orig = (bid & 7) * 512 + (bid >> 3);   // bijective XCD swizzle (4096 blocks)
    const int h    = orig >> 8;                      // 2 heads per XCD
    const int rem  = orig & 255;
    const int qt   = rem >> 1;
    const int b    = rem & 1;                        // b-pair adjacent -> bias L2 share
    const int bh   = b * NH + h;
    const int qbase = qt * 16;
    const int kw   = w * KSPAN;

    const float* kbh = kp + (size_t)bh * SEQ * DH;
    const float* vbh = vp + (size_t)bh * SEQ * DH;
    char* pivot = (char*)&ArenaH[w][0];              // 16 rows x 128B (f16)
    char* pbig  = (char*)Pbig;

    // Q fragment (B-operand of swapped QK^T), prescaled by 1/8
    bf16x8 qf0, qf1;
    {
        const float* qb = qp + ((size_t)bh * SEQ + qbase + l15) * DH + g * 8;
        #pragma unroll
        for (int j = 0; j < 8; ++j) {
            qf0[j] = (short)f2bf(qb[j]      * 0.125f);
            qf1[j] = (short)f2bf(qb[32 + j] * 0.125f);
        }
    }

    struct KS { f32x4 k[2][4]; };
    auto load_k = [&](int tk, KS& R) {               // tk = subtile idx 0..7 in wave span
        const int kb = kw + tk * SUBT;
        #pragma unroll
        for (int mb = 0; mb < 2; ++mb) {
            const float* arow = kbh + (size_t)(kb + 16 * mb + l15) * DH + g * 8;
            R.k[mb][0] = *(const f32x4*)(arow);
            R.k[mb][1] = *(const f32x4*)(arow + 4);
            R.k[mb][2] = *(const f32x4*)(arow + 32);
            R.k[mb][3] = *(const f32x4*)(arow + 36);
        }
    };

    auto produce = [&](const KS& R, int s2) {        // s2 = subtile within chunk (0/1)
        #pragma unroll
        for (int mb = 0; mb < 2; ++mb) {
            union { bf16x8 v; unsigned int u[4]; } A0, A1;
            A0.u[0] = pkt(R.k[mb][0][0], R.k[mb][0][1]);
            A0.u[1] = pkt(R.k[mb][0][2], R.k[mb][0][3]);
            A0.u[2] = pkt(R.k[mb][1][0], R.k[mb][1][1]);
            A0.u[3] = pkt(R.k[mb][1][2], R.k[mb][1][3]);
            A1.u[0] = pkt(R.k[mb][2][0], R.k[mb][2][1]);
            A1.u[1] = pkt(R.k[mb][2][2], R.k[mb][2][3]);
            A1.u[2] = pkt(R.k[mb][3][0], R.k[mb][3][1]);
            A1.u[3] = pkt(R.k[mb][3][2], R.k[mb][3][3]);
            f32x4 c = (f32x4){0.f, 0.f, 0.f, 0.f};
            __builtin_amdgcn_s_setprio(1);
            c = __builtin_amdgcn_mfma_f32_16x16x32_bf16(A0.v, qf0, c, 0, 0, 0);
            c = __builtin_amdgcn_mfma_f32_16x16x32_bf16(A1.v, qf1, c, 0, 0, 0);
            __builtin_amdgcn_s_setprio(0);
            // raw scores (pre-bias, |s|<~6) -> f16 pivot (RNE), 8B per lane
            union { f16x4 h; u32x2 u; } hc;
            hc.h[0] = (_Float16)c[0];  hc.h[1] = (_Float16)c[1];
            hc.h[2] = (_Float16)c[2];  hc.h[3] = (_Float16)c[3];
            const int byo = (64 * s2 + 32 * mb + 8 * g) ^ ((l15 & 7) << 4);
            *(u32x2*)(pivot + l15 * 128 + byo) = hc.u;
        }
    };

    auto load_bias = [&](int c, f32x4* B) {          // contiguous: 4 rows x 256B per instr
        #pragma unroll
        for (int i = 0; i < 4; ++i)
            B[i] = *(const f32x4*)(bp + ((size_t)h * SEQ + qbase + 4 * i + g) * SEQ
                                   + kw + c * CHUNK + 4 * l15);
    };

    float rs[4] = {0.f, 0.f, 0.f, 0.f};              // row partials (row = 4i+g)

    auto consume = [&](int c, const f32x4* B) {
        #pragma unroll
        for (int i = 0; i < 4; ++i) {
            const int qr = 4 * i + g;                // local row 0..15
            int m4[4];
            if constexpr (ISBYTE) {
                unsigned int mk = *(const unsigned int*)((const unsigned char*)mp +
                    ((size_t)b * SEQ + qbase + qr) * SEQ + kw + c * CHUNK + 4 * l15);
                #pragma unroll
                for (int j = 0; j < 4; ++j) m4[j] = (int)((mk >> (8 * j)) & 0xFFu);
            } else {
                i32x4 mk = *(const i32x4*)((const int*)mp +
                    ((size_t)b * SEQ + qbase + qr) * SEQ + kw + c * CHUNK + 4 * l15);
                #pragma unroll
                for (int j = 0; j < 4; ++j) m4[j] = mk[j];
            }
            union { u32x2 u; f16x4 hh; } hv;
            hv.u = *(const u32x2*)(pivot + qr * 128 + ((8 * l15) ^ ((qr & 7) << 4)));
            f32x4 pa;
            #pragma unroll
            for (int j = 0; j < 4; ++j)
                pa[j] = m4[j] ? 0.0f : __expf((float)hv.hh[j] + B[i][j]);
            rs[i] += pa[0] + pa[1] + pa[2] + pa[3];
            u32x2 pw;
            pw[0] = pkt(pa[0], pa[1]);
            pw[1] = pkt(pa[2], pa[3]);
            const int byo = (2 * kw + 128 * c + 8 * l15) ^ ((qr & 7) << 4);
            *(u32x2*)(pbig + qr * 4096 + byo) = pw;
        }
    };

    f32x4 accO[4];   // accO[nb][rr] = O[q=qbase+4g+rr][d=16nb+l15] (this wave's k-span)
    #pragma unroll
    for (int i = 0; i < 4; ++i) accO[i] = (f32x4){0.f, 0.f, 0.f, 0.f};

    auto pv = [&](int c) {
        #pragma unroll
        for (int ks2 = 0; ks2 < 2; ++ks2) {
            const int colg = kw + (2 * c + ks2) * SUBT;
            const int byo = (2 * colg + 16 * g) ^ ((l15 & 7) << 4);
            bf16x8 pf = *(const bf16x8*)(pbig + l15 * 4096 + byo);
            const float* vb2 = vbh + (size_t)colg * DH + 512 * g + l15;
            union { bf16x8 v; unsigned int u[4]; } vf[4];
            #pragma unroll
            for (int nb = 0; nb < 4; ++nb)
                #pragma unroll
                for (int i2 = 0; i2 < 4; ++i2)
                    vf[nb].u[i2] = pkt(vb2[(2 * i2) * 64 + 16 * nb],
                                       vb2[(2 * i2 + 1) * 64 + 16 * nb]);
            __builtin_amdgcn_s_setprio(1);
            #pragma unroll
            for (int nb = 0; nb < 4; ++nb)
                accO[nb] = __builtin_amdgcn_mfma_f32_16x16x32_bf16(pf, vf[nb].v, accO[nb], 0, 0, 0);
            __builtin_amdgcn_s_setprio(0);
        }
    };

    // ================= phase 1: 4 chunks, bias D=1-ahead, K D=2 ring =================
    {
        KS RA, RB;
        f32x4 BA[4], BB[4];
        load_k(0, RA);
        load_k(1, RB);
        load_bias(0, BA);

        #pragma unroll
        for (int c = 0; c < NCHK; ++c) {
            f32x4* Bcur = (c & 1) ? BB : BA;
            f32x4* Bnxt = (c & 1) ? BA : BB;
            if (c < NCHK - 1) load_bias(c + 1, Bnxt);
            produce(RA, 0);  load_k((2 * c + 2) & 7, RA);
            produce(RB, 1);  load_k((2 * c + 3) & 7, RB);
            consume(c, Bcur);
            pv(c);
        }
    }

    // row-sum partials -> Lsum overlay on own (dead) pivot
    {
        float* lsw = (float*)&ArenaH[w][0];
        #pragma unroll
        for (int i = 0; i < 4; ++i) {
            float t = rs[i];
            t += __shfl_xor(t, 1, 64);
            t += __shfl_xor(t, 2, 64);
            t += __shfl_xor(t, 4, 64);
            t += __shfl_xor(t, 8, 64);
            if (l15 == 0) lsw[4 * i + g] = t;
        }
    }

    __syncthreads();                                 // barrier 1: Lsum ready

    // ================= phase 2: normalize own span, write attn ONCE =================
    float rv[4];
    #pragma unroll
    for (int i = 0; i < 4; ++i) {
        float s = 0.f;
        #pragma unroll
        for (int ww = 0; ww < NW; ++ww) s += ((const float*)&ArenaH[ww][0])[4 * i + g];
        rv[i] = 1.0f / s;
    }

    #pragma unroll
    for (int i = 0; i < 4; ++i) {
        const int qr = 4 * i + g;
        #pragma unroll
        for (int u = 0; u < 2; ++u) {
            const int byo = (2 * kw + 256 * u + 16 * l15) ^ ((qr & 7) << 4);
            bf16x8 pb8 = *(const bf16x8*)(pbig + qr * 4096 + byo);
            f32x4 o0, o1;
            #pragma unroll
            for (int j = 0; j < 4; ++j) {
                o0[j] = bfu2f((unsigned short)pb8[j])     * rv[i];
                o1[j] = bfu2f((unsigned short)pb8[4 + j]) * rv[i];
            }
            float* ap = attnp + ((size_t)bh * SEQ + qbase + qr) * SEQ
                        + kw + u * 128 + 8 * l15;
            *(f32x4*)ap       = o0;
            *(f32x4*)(ap + 4) = o1;
        }
    }

    __syncthreads();                                 // barrier 2: Pbig fully dead

    // accO deposit into Pbig (4 KB per wave), then wave 0 combines
    {
        float* dep = (float*)pbig + w * 1024;
        #pragma unroll
        for (int rr = 0; rr < 4; ++rr)
            #pragma unroll
            for (int nb = 0; nb < 4; ++nb)
                dep[(4 * g + rr) * 64 + 16 * nb + l15] = accO[nb][rr];
    }

    __syncthreads();                                 // barrier 3: deposits visible

    if (w == 0) {
        const int d = lane;
        #pragma unroll
        for (int r = 0; r < 16; ++r) {
            float s = 0.f, o = 0.f;
            #pragma unroll
            for (int ww = 0; ww < NW; ++ww) {
                s += ((const float*)&ArenaH[ww][0])[r];
                o += ((const float*)pbig)[ww * 1024 + r * 64 + d];
            }
            outp[((size_t)bh * SEQ + qbase + r) * DH + d] = o / s;
        }
    }
}

extern "C" void kernel_launch(void* const* d_in, const int* in_sizes, int n_in,
                              void* d_out, int out_size, void* d_ws, size_t ws_size,
                              hipStream_t stream) {
    const float* qp = (const float*)d_in[0];
    const float* kp = (const float*)d_in[1];
    const float* vp = (const float*)d_in[2];
    const void*  mp = d_in[3];
    const float* bp = (const float*)d_in[4];

    float* outp  = (float*)d_out;
    float* attnp = outp + (size_t)BATCH * NH * SEQ * DH;   // out first, then attn (f32)

    dim3 grid(BATCH * NH * (SEQ / 16)), block(512);        // 4096 blocks x 8 waves
    // mask layout resolved on-device; mismatched instantiation exits immediately
    sdpa_fused<true ><<<grid, block, 0, stream>>>(qp, kp, vp, mp, bp, outp, attnp);
    sdpa_fused<false><<<grid, block, 0, stream>>>(qp, kp, vp, mp, bp, outp, attnp);
}